// Round 12
// baseline (108.215 us; speedup 1.0000x reference)
//
#include <hip/hip_runtime.h>
#include <math.h>

// ECE loss: per-row softmax-max confidence + argmax prediction, binned
// histogram over (pred_class, conf_bin) cells, ECE = sum|sum_conf-sum_acc|/N.
//
// Round-12 = round-11 (NT staging, 53KB tiles, 2 blk/CU, 84.1 us) with the
// COVERAGE lever: 384-thread blocks, 96-row tiles (39.9KB stage + 12KB hist
// = 51.9KB -> 3 blocks/CU, 18 waves/CU). During any block's serial
// consume+drain phase, 2 other resident blocks (not 1) keep the CU's load
// queue fed. Bytes-per-barrier only drops 53->40KB (flat part of the r10/r11
// curve). Consume: quad-per-row, 96 quads = 384 threads, no idle lanes.
//
// N = 1,000,000; 96-row tiles -> 10417 tiles, last tile 64 rows (guarded).
// Workspace (d_ws as float*): [0..NCELLS) sum_conf, [NCELLS..2*NCELLS) sum_acc.

constexpr int C  = 100;
constexpr int NB = 15;
constexpr int NCELLS = C * NB;          // 1500
constexpr int ROWS = 96;                // rows per tile
constexpr int F4R  = 25;                // float4 per row
constexpr int STR  = 26;                // padded LDS row stride (416 B)
constexpr int TILE_F4 = ROWS * STR;     // 2496
constexpr int THREADS = 384;            // 6 waves
constexpr int GRID_MAIN = 768;          // 3 blocks/CU x 256 CU

__global__ void ece_zero(float* __restrict__ ws, int n) {
    int i = blockIdx.x * blockDim.x + threadIdx.x;
    if (i < n) ws[i] = 0.0f;
}

__device__ __forceinline__ void load_lds_16B_nt(const void* gsrc, void* ldst) {
    // aux=2: CPol NT (non-temporal) on gfx950 — stream, evict-first.
    __builtin_amdgcn_global_load_lds(
        (const __attribute__((address_space(1))) void*)gsrc,
        (__attribute__((address_space(3))) void*)ldst, 16, 0, 2);
}

__global__ __launch_bounds__(THREADS)
void ece_main(const float* __restrict__ logits,
              const int* __restrict__ labels,
              int N, int ntiles, float* __restrict__ cellsums) {
    __shared__ float4 stage[TILE_F4];     // 39936 B
    __shared__ float  hist[2 * NCELLS];   // 12000 B -> 51.9 KB, 3 blocks/CU

    for (int i = threadIdx.x; i < 2 * NCELLS; i += THREADS) hist[i] = 0.0f;

    const int tid  = threadIdx.x;
    const int l4   = tid & 3;
    const int qg   = tid >> 2;            // 0..95: row-in-tile owned by quad
    const int wbase = (tid >> 6) << 6;    // wave-uniform slot base

    // Tile-invariant stage descriptors: slot s = i*384+tid -> (r=s/26, c=s%26);
    // c==25 is pad (skip). Source f4 offset r*25+c; rrow kept for the N-guard.
    int offs[7], rrow[7]; bool val[7];
    #pragma unroll
    for (int i = 0; i < 7; ++i) {
        int s = i * THREADS + tid;
        int r = s / STR, c = s - r * STR;
        val[i]  = (s < TILE_F4) && (c < F4R);
        offs[i] = r * F4R + c;
        rrow[i] = r;
    }

    const float4* logits4 = reinterpret_cast<const float4*>(logits);
    constexpr float LOG2E = 1.4426950408889634f;

    for (int tile = blockIdx.x; tile < ntiles; tile += gridDim.x) {
        const int row0 = tile * ROWS;
        const float4* tb = logits4 + (size_t)row0 * F4R;

        // ---- stage: contiguous NT stream -> padded LDS tile ----
        #pragma unroll
        for (int i = 0; i < 7; ++i) {
            if (val[i] && (row0 + rrow[i]) < N)
                load_lds_16B_nt(tb + offs[i], &stage[i * THREADS + wbase]);
        }
        __syncthreads();   // tile staged

        // ---- consume: quad (4 lanes) per row ----
        const int row = row0 + qg;
        if (row < N) {
            int lab = -1;
            if (l4 == 0) lab = __builtin_nontemporal_load(&labels[row]);

            const float4* rp = &stage[qg * STR];
            float4 v[6];
            #pragma unroll
            for (int j = 0; j < 6; ++j) v[j] = rp[l4 + 4 * j];
            float4 v6;
            const bool has7 = (l4 == 0);
            if (has7) v6 = rp[24];

            // pass 1: per-lane max + first-occurrence argmax
            float m = -INFINITY;
            int   am = 0;
            #pragma unroll
            for (int j = 0; j < 6; ++j) {
                int base = (l4 + 4 * j) * 4;
                if (v[j].x > m) { m = v[j].x; am = base + 0; }
                if (v[j].y > m) { m = v[j].y; am = base + 1; }
                if (v[j].z > m) { m = v[j].z; am = base + 2; }
                if (v[j].w > m) { m = v[j].w; am = base + 3; }
            }
            if (has7) {
                if (v6.x > m) { m = v6.x; am = 96; }
                if (v6.y > m) { m = v6.y; am = 97; }
                if (v6.z > m) { m = v6.z; am = 98; }
                if (v6.w > m) { m = v6.w; am = 99; }
            }
            #pragma unroll
            for (int off = 1; off < 4; off <<= 1) {
                float om  = __shfl_xor(m, off, 64);
                int   oam = __shfl_xor(am, off, 64);
                if (om > m || (om == m && oam < am)) { m = om; am = oam; }
            }

            // pass 2: sum exp(x-m) = exp2(x*log2e - m*log2e)
            const float ml = m * LOG2E;
            float s = 0.0f;
            #pragma unroll
            for (int j = 0; j < 6; ++j) {
                s += exp2f(__fmaf_rn(v[j].x, LOG2E, -ml))
                   + exp2f(__fmaf_rn(v[j].y, LOG2E, -ml))
                   + exp2f(__fmaf_rn(v[j].z, LOG2E, -ml))
                   + exp2f(__fmaf_rn(v[j].w, LOG2E, -ml));
            }
            if (has7) {
                s += exp2f(__fmaf_rn(v6.x, LOG2E, -ml))
                   + exp2f(__fmaf_rn(v6.y, LOG2E, -ml))
                   + exp2f(__fmaf_rn(v6.z, LOG2E, -ml))
                   + exp2f(__fmaf_rn(v6.w, LOG2E, -ml));
            }
            #pragma unroll
            for (int off = 1; off < 4; off <<= 1) s += __shfl_xor(s, off, 64);

            if (l4 == 0) {
                float conf = 1.0f / s;
                int b = (int)ceilf(conf * (float)NB) - 1;
                b = b < 0 ? 0 : (b > NB - 1 ? NB - 1 : b);
                int cell = am * NB + b;
                atomicAdd(&hist[cell], conf);
                if (lab == am) atomicAdd(&hist[NCELLS + cell], 1.0f);
            }
        }
        __syncthreads();   // protect stage buffer before next overwrite
    }

    // flush per-block histogram
    for (int i = threadIdx.x; i < 2 * NCELLS; i += THREADS) {
        float v = hist[i];
        if (v != 0.0f) atomicAdd(&cellsums[i], v);
    }
}

__global__ void ece_final(const float* __restrict__ cellsums,
                          float invN, float* __restrict__ out) {
    __shared__ float red[256];
    float t = 0.0f;
    for (int i = threadIdx.x; i < NCELLS; i += blockDim.x)
        t += fabsf(cellsums[i] - cellsums[NCELLS + i]);
    red[threadIdx.x] = t;
    __syncthreads();
    for (int w = 128; w > 0; w >>= 1) {
        if (threadIdx.x < w) red[threadIdx.x] += red[threadIdx.x + w];
        __syncthreads();
    }
    if (threadIdx.x == 0) out[0] = red[0] * invN;
}

extern "C" void kernel_launch(void* const* d_in, const int* in_sizes, int n_in,
                              void* d_out, int out_size, void* d_ws, size_t ws_size,
                              hipStream_t stream) {
    const float* logits = (const float*)d_in[0];
    const int*   labels = (const int*)d_in[1];

    const int N = in_sizes[1];                     // 1,000,000
    const int ntiles = (N + ROWS - 1) / ROWS;      // 10417 (last tile: 64 rows)

    float* cellsums = (float*)d_ws;
    float* out = (float*)d_out;

    // 1) zero global cell accumulators (harness poisons ws, never re-zeroes)
    {
        int n = 2 * NCELLS;
        ece_zero<<<(n + 255) / 256, 256, 0, stream>>>(cellsums, n);
    }

    // 2) main pass: NT staging, 96-row tiles, 3 blocks/CU
    ece_main<<<GRID_MAIN, THREADS, 0, stream>>>(logits, labels, N, ntiles, cellsums);

    // 3) finalize
    ece_final<<<1, 256, 0, stream>>>(cellsums, 1.0f / (float)N, out);
}

// Round 13
// 84.376 us; speedup vs baseline: 1.2825x; 1.2825x over previous
//
#include <hip/hip_runtime.h>
#include <math.h>

// ECE loss: per-row softmax-max confidence + argmax prediction, binned
// histogram over (pred_class, conf_bin) cells, ECE = sum|sum_conf-sum_acc|/N.
//
// FINAL (= round-11, the best of 13 tested variants, 84.12 us):
//   - global_load_lds staging with NT cache policy (aux=2): the stream is
//     read-once; NT avoids L1/L2/L3 dead-line allocation (+9% vs default).
//   - 128-row tiles (53.2 KB stage): largest bytes-per-barrier-drain at
//     2 blocks/CU; the serial stage->sync->consume structure beat every
//     pipelined variant (depth-1/2/3, counted vmcnt, reg-staging all slower).
//   - quad-per-row consume from LDS (stride-26 f4 rows, 2-way bank aliasing
//     = free), two-pass max/argmax + exp2(fma) softmax, 2-round shuffles.
//   - per-block LDS histogram (1500 cells x {conf,acc}), global atomic flush,
//     single-block finalize.
//
// Effective BW ~5.15 TB/s (~82% of 6.3 TB/s achievable); FETCH ~= ideal
// 404 MB; bank conflicts 0; VALUBusy ~13% (compute fully hidden).
//
// N = 1,000,000; 128-row tiles -> 7813 tiles, last tile 64 rows (guarded).
// Workspace (d_ws as float*): [0..NCELLS) sum_conf, [NCELLS..2*NCELLS) sum_acc.

constexpr int C  = 100;
constexpr int NB = 15;
constexpr int NCELLS = C * NB;          // 1500
constexpr int ROWS = 128;               // rows per tile
constexpr int F4R  = 25;                // float4 per row
constexpr int STR  = 26;                // padded LDS row stride (416 B)
constexpr int TILE_F4 = ROWS * STR;     // 3328
constexpr int THREADS = 512;
constexpr int GRID_MAIN = 512;          // 2 blocks/CU x 256 CU

__global__ void ece_zero(float* __restrict__ ws, int n) {
    int i = blockIdx.x * blockDim.x + threadIdx.x;
    if (i < n) ws[i] = 0.0f;
}

__device__ __forceinline__ void load_lds_16B_nt(const void* gsrc, void* ldst) {
    // aux=2: CPol NT (non-temporal) on gfx950 — stream, evict-first.
    __builtin_amdgcn_global_load_lds(
        (const __attribute__((address_space(1))) void*)gsrc,
        (__attribute__((address_space(3))) void*)ldst, 16, 0, 2);
}

__global__ __launch_bounds__(THREADS)
void ece_main(const float* __restrict__ logits,
              const int* __restrict__ labels,
              int N, int ntiles, float* __restrict__ cellsums) {
    __shared__ float4 stage[TILE_F4];     // 53248 B
    __shared__ float  hist[2 * NCELLS];   // 12000 B -> 65.2 KB, 2 blocks/CU

    for (int i = threadIdx.x; i < 2 * NCELLS; i += THREADS) hist[i] = 0.0f;

    const int tid  = threadIdx.x;
    const int l4   = tid & 3;
    const int qg   = tid >> 2;            // 0..127: row-in-tile owned by quad
    const int wbase = (tid >> 6) << 6;    // wave-uniform slot base

    // Tile-invariant stage descriptors: slot s = i*512+tid -> (r=s/26, c=s%26);
    // c==25 is pad (skip). Source f4 offset r*25+c; rrow kept for the N-guard.
    int offs[7], rrow[7]; bool val[7];
    #pragma unroll
    for (int i = 0; i < 7; ++i) {
        int s = i * 512 + tid;
        int r = s / STR, c = s - r * STR;
        val[i]  = (s < TILE_F4) && (c < F4R);
        offs[i] = r * F4R + c;
        rrow[i] = r;
    }

    const float4* logits4 = reinterpret_cast<const float4*>(logits);
    constexpr float LOG2E = 1.4426950408889634f;

    for (int tile = blockIdx.x; tile < ntiles; tile += gridDim.x) {
        const int row0 = tile * ROWS;
        const float4* tb = logits4 + (size_t)row0 * F4R;

        // ---- stage: contiguous NT stream -> padded LDS tile ----
        #pragma unroll
        for (int i = 0; i < 7; ++i) {
            if (val[i] && (row0 + rrow[i]) < N)
                load_lds_16B_nt(tb + offs[i], &stage[i * 512 + wbase]);
        }
        __syncthreads();   // tile staged

        // ---- consume: quad (4 lanes) per row ----
        const int row = row0 + qg;
        if (row < N) {
            int lab = -1;
            if (l4 == 0) lab = __builtin_nontemporal_load(&labels[row]);

            const float4* rp = &stage[qg * STR];
            float4 v[6];
            #pragma unroll
            for (int j = 0; j < 6; ++j) v[j] = rp[l4 + 4 * j];
            float4 v6;
            const bool has7 = (l4 == 0);
            if (has7) v6 = rp[24];

            // pass 1: per-lane max + first-occurrence argmax
            float m = -INFINITY;
            int   am = 0;
            #pragma unroll
            for (int j = 0; j < 6; ++j) {
                int base = (l4 + 4 * j) * 4;
                if (v[j].x > m) { m = v[j].x; am = base + 0; }
                if (v[j].y > m) { m = v[j].y; am = base + 1; }
                if (v[j].z > m) { m = v[j].z; am = base + 2; }
                if (v[j].w > m) { m = v[j].w; am = base + 3; }
            }
            if (has7) {
                if (v6.x > m) { m = v6.x; am = 96; }
                if (v6.y > m) { m = v6.y; am = 97; }
                if (v6.z > m) { m = v6.z; am = 98; }
                if (v6.w > m) { m = v6.w; am = 99; }
            }
            #pragma unroll
            for (int off = 1; off < 4; off <<= 1) {
                float om  = __shfl_xor(m, off, 64);
                int   oam = __shfl_xor(am, off, 64);
                if (om > m || (om == m && oam < am)) { m = om; am = oam; }
            }

            // pass 2: sum exp(x-m) = exp2(x*log2e - m*log2e)
            const float ml = m * LOG2E;
            float s = 0.0f;
            #pragma unroll
            for (int j = 0; j < 6; ++j) {
                s += exp2f(__fmaf_rn(v[j].x, LOG2E, -ml))
                   + exp2f(__fmaf_rn(v[j].y, LOG2E, -ml))
                   + exp2f(__fmaf_rn(v[j].z, LOG2E, -ml))
                   + exp2f(__fmaf_rn(v[j].w, LOG2E, -ml));
            }
            if (has7) {
                s += exp2f(__fmaf_rn(v6.x, LOG2E, -ml))
                   + exp2f(__fmaf_rn(v6.y, LOG2E, -ml))
                   + exp2f(__fmaf_rn(v6.z, LOG2E, -ml))
                   + exp2f(__fmaf_rn(v6.w, LOG2E, -ml));
            }
            #pragma unroll
            for (int off = 1; off < 4; off <<= 1) s += __shfl_xor(s, off, 64);

            if (l4 == 0) {
                float conf = 1.0f / s;
                int b = (int)ceilf(conf * (float)NB) - 1;
                b = b < 0 ? 0 : (b > NB - 1 ? NB - 1 : b);
                int cell = am * NB + b;
                atomicAdd(&hist[cell], conf);
                if (lab == am) atomicAdd(&hist[NCELLS + cell], 1.0f);
            }
        }
        __syncthreads();   // protect stage buffer before next overwrite
    }

    // flush per-block histogram
    for (int i = threadIdx.x; i < 2 * NCELLS; i += THREADS) {
        float v = hist[i];
        if (v != 0.0f) atomicAdd(&cellsums[i], v);
    }
}

__global__ void ece_final(const float* __restrict__ cellsums,
                          float invN, float* __restrict__ out) {
    __shared__ float red[256];
    float t = 0.0f;
    for (int i = threadIdx.x; i < NCELLS; i += blockDim.x)
        t += fabsf(cellsums[i] - cellsums[NCELLS + i]);
    red[threadIdx.x] = t;
    __syncthreads();
    for (int w = 128; w > 0; w >>= 1) {
        if (threadIdx.x < w) red[threadIdx.x] += red[threadIdx.x + w];
        __syncthreads();
    }
    if (threadIdx.x == 0) out[0] = red[0] * invN;
}

extern "C" void kernel_launch(void* const* d_in, const int* in_sizes, int n_in,
                              void* d_out, int out_size, void* d_ws, size_t ws_size,
                              hipStream_t stream) {
    const float* logits = (const float*)d_in[0];
    const int*   labels = (const int*)d_in[1];

    const int N = in_sizes[1];                     // 1,000,000
    const int ntiles = (N + ROWS - 1) / ROWS;      // 7813 (last tile: 64 rows)

    float* cellsums = (float*)d_ws;
    float* out = (float*)d_out;

    // 1) zero global cell accumulators (harness poisons ws, never re-zeroes)
    {
        int n = 2 * NCELLS;
        ece_zero<<<(n + 255) / 256, 256, 0, stream>>>(cellsums, n);
    }

    // 2) main pass: NT staging, 128-row tiles, 2 blocks/CU
    ece_main<<<GRID_MAIN, THREADS, 0, stream>>>(logits, labels, N, ntiles, cellsums);

    // 3) finalize
    ece_final<<<1, 256, 0, stream>>>(cellsums, 1.0f / (float)N, out);
}